// Round 5
// baseline (1374.330 us; speedup 1.0000x reference)
//
#include <hip/hip_runtime.h>
#include <hip/hip_bf16.h>

#define B_ 2
#define S_ 1024
#define D_ 1024
#define H_ 16
#define K_ 33
#define DH 64
#define SCALE 0.07216878364870322f  // 1/sqrt(3*64)

// ---------- dtype helpers ----------
__device__ __forceinline__ float b2f(unsigned short u) {
    return __uint_as_float(((unsigned int)u) << 16);
}
__device__ __forceinline__ unsigned short f2b(float f) {  // RNE
    unsigned int u = __float_as_uint(f);
    u += 0x7FFFu + ((u >> 16) & 1u);
    return (unsigned short)(u >> 16);
}
__device__ __forceinline__ float ldf(const void* p, int i, int f32) {
    return f32 ? ((const float*)p)[i] : b2f(((const unsigned short*)p)[i]);
}
__device__ __forceinline__ float4 ldf4(const void* p, int i, int f32) {  // i % 4 == 0
    if (f32) return *(const float4*)((const float*)p + i);
    ushort4 u = *(const ushort4*)((const unsigned short*)p + i);
    return make_float4(b2f(u.x), b2f(u.y), b2f(u.z), b2f(u.w));
}
__device__ __forceinline__ float4 ldb4(const unsigned short* p, int i) {  // bf16 buffer
    ushort4 u = *(const ushort4*)(p + i);
    return make_float4(b2f(u.x), b2f(u.y), b2f(u.z), b2f(u.w));
}

// ---------------- prep: sniff dtypes, build mflag ----------------
__global__ __launch_bounds__(256) void prep(const void* __restrict__ hidden,
                                            const void* __restrict__ mask,
                                            int* __restrict__ flags,
                                            float* __restrict__ mflag) {
    __shared__ int cnt;
    __shared__ int mev[6];
    const int t = threadIdx.x;
    if (t == 0) cnt = 0;
    if (t < 6) mev[t] = 0;
    __syncthreads();
    // float dtype sniff: bf16-view exponents of first 2048 16-bit words of hidden.
    // f32 buffer -> low-16 mantissa words are ~uniform -> ~45% have exp field >= 0x8E.
    // bf16 buffer of N(0,1)-scale data -> none.
    const unsigned short* hu = (const unsigned short*)hidden;
    int c = 0;
    for (int i = t; i < 2048; i += 256) {
        int e = (hu[i] >> 7) & 0xFF;
        if (e >= 0x8E) c++;
    }
    if (c) atomicAdd(&cnt, c);
    // mask dtype evidence ladder over first 2048 bytes
    const unsigned char* mb = (const unsigned char*)mask;
    int e_bf = 0, e_f32 = 0, e_f64 = 0, e_f16 = 0, e_u8 = 0;
    for (int p = t; p < 2048; p += 256) {
        unsigned char v = mb[p];
        if ((p & 7) == 6 && v == 0xF0) e_f64 = 1;
        if ((p & 3) == 1 && v == 0x3F) e_bf = 1;
        if ((p & 3) == 3 && v == 0x3F) e_f32 = 1;
        if ((p & 1) == 1 && v == 0x3C) e_f16 = 1;
        if ((p & 3) != 0 && v != 0) e_u8 = 1;
    }
    if (e_f64) atomicOr(&mev[5], 1);
    if (e_bf)  atomicOr(&mev[3], 1);
    if (e_f32) atomicOr(&mev[2], 1);
    if (e_f16) atomicOr(&mev[4], 1);
    if (e_u8)  atomicOr(&mev[1], 1);
    __syncthreads();
    const int f32flag = (cnt >= 8) ? 1 : 0;
    const int mm = mev[5] ? 5 : (mev[3] ? 3 : (mev[2] ? 2 : (mev[4] ? 4 : (mev[1] ? 1 : 0))));
    if (t == 0) { flags[0] = f32flag; flags[2] = mm; }
    for (int j = t; j < B_ * S_; j += 256) {
        int m;
        if (mm == 5)      m = (((const double*)mask)[j] != 0.0);
        else if (mm == 3 || mm == 4) m = (((const unsigned short*)mask)[j] != 0);
        else if (mm == 2) m = (((const float*)mask)[j] != 0.f);
        else if (mm == 1) m = (mb[j] != 0);
        else              m = (((const int*)mask)[j] != 0);
        mflag[j] = m ? 1.f : 0.f;
    }
}

// ---------------- GEMM: QKV projection, bf16 output permuted to [B,H,S,d] ----------------
__global__ __launch_bounds__(256) void gemm_qkv(const void* __restrict__ X,
                                                const void* __restrict__ W,
                                                const void* __restrict__ bias,
                                                const int* __restrict__ flags,
                                                unsigned short* __restrict__ outp) {
    __shared__ float As[16][68];
    __shared__ float Bs[16][68];
    const int f32u = flags[0];
    const int m0 = blockIdx.y * 64, n0 = blockIdx.x * 64;
    const int t = threadIdx.x;
    const int tm = t >> 4, tn = t & 15;
    float acc[4][4] = {};
    for (int k0 = 0; k0 < 1024; k0 += 16) {
        {
            int c = t & 15, r = t >> 4;
#pragma unroll
            for (int qq = 0; qq < 4; ++qq)
                As[c][r + 16 * qq] = ldf(X, (m0 + r + 16 * qq) * 1024 + k0 + c, f32u);
            int j = t & 63, cb = t >> 6;
#pragma unroll
            for (int qq = 0; qq < 4; ++qq)
                Bs[cb + 4 * qq][j] = ldf(W, (k0 + cb + 4 * qq) * 1024 + n0 + j, f32u);
        }
        __syncthreads();
#pragma unroll
        for (int k = 0; k < 16; ++k) {
            float4 a = *(const float4*)&As[k][tm * 4];
            float4 b = *(const float4*)&Bs[k][tn * 4];
            float av[4] = {a.x, a.y, a.z, a.w};
            float bv[4] = {b.x, b.y, b.z, b.w};
#pragma unroll
            for (int i = 0; i < 4; ++i)
#pragma unroll
                for (int j = 0; j < 4; ++j) acc[i][j] += av[i] * bv[j];
        }
        __syncthreads();
    }
#pragma unroll
    for (int i = 0; i < 4; ++i) {
        int m = m0 + tm * 4 + i;
        int bb = m >> 10, ii = m & 1023;
#pragma unroll
        for (int j = 0; j < 4; ++j) {
            int n = n0 + tn * 4 + j;
            int hh = n >> 6, dd = n & 63;
            outp[((bb * H_ + hh) * S_ + ii) * DH + dd] = f2b(acc[i][j] + ldf(bias, n, f32u));
        }
    }
}

// ---------------- Final GEMM: bf16 ctx @ Wo + bo -> f32 d_out ----------------
__global__ __launch_bounds__(256) void gemm_out(const unsigned short* __restrict__ X,
                                                const void* __restrict__ W,
                                                const void* __restrict__ bias,
                                                const int* __restrict__ flags,
                                                float* __restrict__ out) {
    __shared__ float As[16][68];
    __shared__ float Bs[16][68];
    const int f32u = flags[0];
    const int m0 = blockIdx.y * 64, n0 = blockIdx.x * 64;
    const int t = threadIdx.x;
    const int tm = t >> 4, tn = t & 15;
    float acc[4][4] = {};
    for (int k0 = 0; k0 < 1024; k0 += 16) {
        {
            int c = t & 15, r = t >> 4;
#pragma unroll
            for (int qq = 0; qq < 4; ++qq)
                As[c][r + 16 * qq] = b2f(X[(m0 + r + 16 * qq) * 1024 + k0 + c]);
            int j = t & 63, cb = t >> 6;
#pragma unroll
            for (int qq = 0; qq < 4; ++qq)
                Bs[cb + 4 * qq][j] = ldf(W, (k0 + cb + 4 * qq) * 1024 + n0 + j, f32u);
        }
        __syncthreads();
#pragma unroll
        for (int k = 0; k < 16; ++k) {
            float4 a = *(const float4*)&As[k][tm * 4];
            float4 b = *(const float4*)&Bs[k][tn * 4];
            float av[4] = {a.x, a.y, a.z, a.w};
            float bv[4] = {b.x, b.y, b.z, b.w};
#pragma unroll
            for (int i = 0; i < 4; ++i)
#pragma unroll
                for (int j = 0; j < 4; ++j) acc[i][j] += av[i] * bv[j];
        }
        __syncthreads();
    }
#pragma unroll
    for (int i = 0; i < 4; ++i) {
        int m = m0 + tm * 4 + i;
#pragma unroll
        for (int j = 0; j < 4; ++j) {
            int n = n0 + tn * 4 + j;
            out[m * 1024 + n] = acc[i][j] + ldf(bias, n, f32u);
        }
    }
}

// ---------------- raw_p2c (bf16 in/out) ----------------
__global__ __launch_bounds__(256) void rel_p2c(const unsigned short* __restrict__ kws,
                                               const void* __restrict__ relq,
                                               const int* __restrict__ flags,
                                               unsigned short* __restrict__ p2c) {
    __shared__ float kt[64][68];
    __shared__ float rq[33][68];
    const int f32u = flags[0];
    const int bh = blockIdx.y, h = bh & 15;
    const int j0 = blockIdx.x * 64;
    const int t = threadIdx.x;
#pragma unroll
    for (int qq = 0; qq < 4; ++qq) {
        int idx = t + 256 * qq;
        int j = idx >> 4, d4 = idx & 15;
        *(float4*)&kt[j][d4 * 4] = ldb4(kws, (bh * S_ + j0 + j) * DH + d4 * 4);
    }
    for (int idx = t; idx < 33 * 16; idx += 256) {
        int k = idx >> 4, d4 = idx & 15;
        *(float4*)&rq[k][d4 * 4] = ldf4(relq, (h * K_ + k) * DH + d4 * 4, f32u);
    }
    __syncthreads();
    for (int o = t; o < 33 * 64; o += 256) {
        int k = o >> 6, j = o & 63;
        float s = 0.f;
#pragma unroll
        for (int d4 = 0; d4 < 16; ++d4) {
            float4 a = *(const float4*)&rq[k][d4 * 4];
            float4 b = *(const float4*)&kt[j][d4 * 4];
            s += a.x * b.x + a.y * b.y + a.z * b.z + a.w * b.w;
        }
        p2c[(bh * K_ + k) * S_ + j0 + j] = f2b(s * SCALE);
    }
}

// ---------------- raw_c2p (bf16 in/out) ----------------
__global__ __launch_bounds__(256) void rel_c2p(const unsigned short* __restrict__ qws,
                                               const void* __restrict__ relk,
                                               const int* __restrict__ flags,
                                               unsigned short* __restrict__ c2p) {
    __shared__ float qt[64][68];
    __shared__ float rk[33][68];
    const int f32u = flags[0];
    const int bh = blockIdx.y, h = bh & 15;
    const int i0 = blockIdx.x * 64;
    const int t = threadIdx.x;
#pragma unroll
    for (int qq = 0; qq < 4; ++qq) {
        int idx = t + 256 * qq;
        int i = idx >> 4, d4 = idx & 15;
        *(float4*)&qt[i][d4 * 4] = ldb4(qws, (bh * S_ + i0 + i) * DH + d4 * 4);
    }
    for (int idx = t; idx < 33 * 16; idx += 256) {
        int k = idx >> 4, d4 = idx & 15;
        *(float4*)&rk[k][d4 * 4] = ldf4(relk, (h * K_ + k) * DH + d4 * 4, f32u);
    }
    __syncthreads();
    for (int o = t; o < 64 * 33; o += 256) {
        int i = o / 33, k = o % 33;
        float s = 0.f;
#pragma unroll
        for (int d4 = 0; d4 < 16; ++d4) {
            float4 a = *(const float4*)&qt[i][d4 * 4];
            float4 b = *(const float4*)&rk[k][d4 * 4];
            s += a.x * b.x + a.y * b.y + a.z * b.z + a.w * b.w;
        }
        c2p[(bh * S_ + i0 + i) * K_ + k] = f2b(s * SCALE);
    }
}

// ---------------- two-pass attention (bf16 staged inputs), f32 math ----------------
__global__ __launch_bounds__(256) void attn_simple(const unsigned short* __restrict__ qws,
                                                   const unsigned short* __restrict__ kws,
                                                   const unsigned short* __restrict__ vws,
                                                   const unsigned short* __restrict__ p2c,
                                                   const unsigned short* __restrict__ c2p,
                                                   const float* __restrict__ mflag,
                                                   const int* __restrict__ pos,
                                                   const void* __restrict__ relv,
                                                   const int* __restrict__ flags,
                                                   unsigned short* __restrict__ ctxo) {
    __shared__ float Ssc[8][1024];
    __shared__ float kt[64][68];
    __shared__ float rvt[33][64];
    __shared__ float qs[8][68];
    __shared__ float c2ps[8][34];
    __shared__ float ag[8][34];

    const int f32u = flags[0];
    const int bh = blockIdx.y, b = bh >> 4, h = bh & 15;
    const int i0 = blockIdx.x * 8;
    const int t = threadIdx.x;
    const int ti = t >> 5;
    const int tw = t & 31;
    const int irow = i0 + ti;

    for (int idx = t; idx < 8 * 16; idx += 256) {
        int i = idx >> 4, d4 = idx & 15;
        *(float4*)&qs[i][d4 * 4] = ldb4(qws, (bh * S_ + i0 + i) * DH + d4 * 4);
    }
    for (int idx = t; idx < 8 * 33; idx += 256) {
        int i = idx / 33, k = idx % 33;
        c2ps[i][k] = b2f(c2p[(bh * S_ + i0 + i) * K_ + k]);
    }
    for (int idx = t; idx < 8 * 34; idx += 256) ag[idx / 34][idx % 34] = 0.f;

    // phase 1: scores
    for (int jt = 0; jt < 16; ++jt) {
        const int j0 = jt * 64;
        __syncthreads();
#pragma unroll
        for (int qq = 0; qq < 4; ++qq) {
            int idx = t + 256 * qq;
            int j = idx >> 4, d4 = idx & 15;
            *(float4*)&kt[j][d4 * 4] = ldb4(kws, (bh * S_ + j0 + j) * DH + d4 * 4);
        }
        for (int idx = t; idx < 33 * 16; idx += 256) {
            int k = idx >> 4, j4 = idx & 15;
            *(float4*)&rvt[k][j4 * 4] = ldb4(p2c, (bh * K_ + k) * S_ + j0 + j4 * 4);
        }
        __syncthreads();
        for (int idx = t; idx < 8 * 64; idx += 256) {
            int i = idx >> 6, j = idx & 63;
            float s = 0.f;
#pragma unroll
            for (int d4 = 0; d4 < 16; ++d4) {
                float4 a = *(const float4*)&qs[i][d4 * 4];
                float4 kv = *(const float4*)&kt[j][d4 * 4];
                s += a.x * kv.x + a.y * kv.y + a.z * kv.z + a.w * kv.w;
            }
            s *= SCALE;
            int pb = pos[(b * S_ + i0 + i) * S_ + j0 + j];
            pb = min(max(pb, 0), K_ - 1);
            s += rvt[pb][j] + c2ps[i][pb];
            if (mflag[b * S_ + j0 + j] != 0.f) s = -1e9f;
            Ssc[i][j0 + j] = s;
        }
    }
    __syncthreads();

    // phase 2: row softmax (unnormalized)
    float m = -1e30f;
    for (int j = tw; j < 1024; j += 32) m = fmaxf(m, Ssc[ti][j]);
#pragma unroll
    for (int off = 1; off < 32; off <<= 1) m = fmaxf(m, __shfl_xor(m, off));
    float sum = 0.f;
    for (int j = tw; j < 1024; j += 32) {
        float e = __expf(Ssc[ti][j] - m);
        Ssc[ti][j] = e;
        sum += e;
    }
#pragma unroll
    for (int off = 1; off < 32; off <<= 1) sum += __shfl_xor(sum, off);
    __syncthreads();

    // phase 3: bucket aggregation
    for (int j = tw; j < 1024; j += 32) {
        int pb = pos[(b * S_ + irow) * S_ + j];
        pb = min(max(pb, 0), K_ - 1);
        atomicAdd(&ag[ti][pb], Ssc[ti][j]);
    }

    // phase 4: ctx = P @ V
    const int d0 = tw * 2;
    float acc0 = 0.f, acc1 = 0.f;
    for (int jt = 0; jt < 16; ++jt) {
        const int j0 = jt * 64;
        __syncthreads();
#pragma unroll
        for (int qq = 0; qq < 4; ++qq) {
            int idx = t + 256 * qq;
            int j = idx >> 4, d4 = idx & 15;
            *(float4*)&kt[j][d4 * 4] = ldb4(vws, (bh * S_ + j0 + j) * DH + d4 * 4);
        }
        __syncthreads();
        for (int j = 0; j < 64; ++j) {
            float p = Ssc[ti][j0 + j];
            acc0 += p * kt[j][d0];
            acc1 += p * kt[j][d0 + 1];
        }
    }

    // phase 5: + agg @ rel_v, normalize, write bf16 ctx
    __syncthreads();
    for (int idx = t; idx < 33 * 16; idx += 256) {
        int k = idx >> 4, d4 = idx & 15;
        *(float4*)&rvt[k][d4 * 4] = ldf4(relv, (h * K_ + k) * DH + d4 * 4, f32u);
    }
    __syncthreads();
    for (int kb = 0; kb < 33; ++kb) {
        float a = ag[ti][kb];
        acc0 += a * rvt[kb][d0];
        acc1 += a * rvt[kb][d0 + 1];
    }
    float inv = 1.0f / sum;
    ctxo[(b * S_ + irow) * D_ + h * DH + d0] = f2b(acc0 * inv);
    ctxo[(b * S_ + irow) * D_ + h * DH + d0 + 1] = f2b(acc1 * inv);
}

// ---------------- launcher ----------------
extern "C" void kernel_launch(void* const* d_in, const int* in_sizes, int n_in,
                              void* d_out, int out_size, void* d_ws, size_t ws_size,
                              hipStream_t stream) {
    const void* hidden = d_in[0];
    const void* pos = d_in[1];
    const void* mask = d_in[2];
    const void* Wq = d_in[3];
    const void* bq = d_in[4];
    const void* Wk = d_in[5];
    const void* bk = d_in[6];
    const void* Wv = d_in[7];
    const void* bv = d_in[8];
    const void* Wo = d_in[9];
    const void* bo = d_in[10];
    const void* rq = d_in[11];
    const void* rk = d_in[12];
    const void* rv = d_in[13];

    unsigned char* wsb = (unsigned char*)d_ws;
    size_t o = 0;
    int* flags = (int*)(wsb + o);            o += 256;
    float* mfl = (float*)(wsb + o);          o += 2048 * 4;
    o = (o + 255) & ~(size_t)255;
    unsigned short* qb   = (unsigned short*)(wsb + o); o += 4194304;
    unsigned short* kb   = (unsigned short*)(wsb + o); o += 4194304;
    unsigned short* vb   = (unsigned short*)(wsb + o); o += 4194304;
    unsigned short* p2cb = (unsigned short*)(wsb + o); o += 2162688;
    unsigned short* c2pb = (unsigned short*)(wsb + o); o += 2162688;
    unsigned short* ctxb = (unsigned short*)(wsb + o); o += 4194304;  // ~21.1 MB total

    float* out = (float*)d_out;
    const int* posi = (const int*)pos;

    dim3 tb(256);
    dim3 gg(16, 32);
    prep<<<dim3(1), tb, 0, stream>>>(hidden, mask, flags, mfl);
    gemm_qkv<<<gg, tb, 0, stream>>>(hidden, Wq, bq, flags, qb);
    gemm_qkv<<<gg, tb, 0, stream>>>(hidden, Wk, bk, flags, kb);
    gemm_qkv<<<gg, tb, 0, stream>>>(hidden, Wv, bv, flags, vb);
    rel_p2c<<<dim3(16, 32), tb, 0, stream>>>(kb, rq, flags, p2cb);
    rel_c2p<<<dim3(16, 32), tb, 0, stream>>>(qb, rk, flags, c2pb);
    attn_simple<<<dim3(128, 32), tb, 0, stream>>>(qb, kb, vb, p2cb, c2pb, mfl, posi, rv,
                                                  flags, ctxb);
    gemm_out<<<gg, tb, 0, stream>>>(ctxb, Wo, bo, flags, out);
}

// Round 6
// 955.917 us; speedup vs baseline: 1.4377x; 1.4377x over previous
//
#include <hip/hip_runtime.h>
#include <hip/hip_bf16.h>

#define B_ 2
#define S_ 1024
#define D_ 1024
#define H_ 16
#define K_ 33
#define DH 64
#define SCALE 0.07216878364870322f  // 1/sqrt(3*64)

typedef __attribute__((ext_vector_type(8))) short bf16x8;
typedef __attribute__((ext_vector_type(4))) float f32x4;

// ---------- dtype helpers ----------
__device__ __forceinline__ float b2f(unsigned short u) {
    return __uint_as_float(((unsigned int)u) << 16);
}
__device__ __forceinline__ unsigned short f2b(float f) {  // RNE
    unsigned int u = __float_as_uint(f);
    u += 0x7FFFu + ((u >> 16) & 1u);
    return (unsigned short)(u >> 16);
}
__device__ __forceinline__ float ldf(const void* p, int i, int f32) {
    return f32 ? ((const float*)p)[i] : b2f(((const unsigned short*)p)[i]);
}
__device__ __forceinline__ float4 ldf4(const void* p, int i, int f32) {  // i % 4 == 0
    if (f32) return *(const float4*)((const float*)p + i);
    ushort4 u = *(const ushort4*)((const unsigned short*)p + i);
    return make_float4(b2f(u.x), b2f(u.y), b2f(u.z), b2f(u.w));
}
__device__ __forceinline__ float4 ldb4(const unsigned short* p, int i) {  // bf16 buffer
    ushort4 u = *(const ushort4*)(p + i);
    return make_float4(b2f(u.x), b2f(u.y), b2f(u.z), b2f(u.w));
}

// ---------------- prep: sniff dtypes, build mflag ----------------
__global__ __launch_bounds__(256) void prep(const void* __restrict__ hidden,
                                            const void* __restrict__ mask,
                                            int* __restrict__ flags,
                                            float* __restrict__ mflag) {
    __shared__ int cnt;
    __shared__ int mev[6];
    const int t = threadIdx.x;
    if (t == 0) cnt = 0;
    if (t < 6) mev[t] = 0;
    __syncthreads();
    const unsigned short* hu = (const unsigned short*)hidden;
    int c = 0;
    for (int i = t; i < 2048; i += 256) {
        int e = (hu[i] >> 7) & 0xFF;
        if (e >= 0x8E) c++;
    }
    if (c) atomicAdd(&cnt, c);
    const unsigned char* mb = (const unsigned char*)mask;
    int e_bf = 0, e_f32 = 0, e_f64 = 0, e_f16 = 0, e_u8 = 0;
    for (int p = t; p < 2048; p += 256) {
        unsigned char v = mb[p];
        if ((p & 7) == 6 && v == 0xF0) e_f64 = 1;
        if ((p & 3) == 1 && v == 0x3F) e_bf = 1;
        if ((p & 3) == 3 && v == 0x3F) e_f32 = 1;
        if ((p & 1) == 1 && v == 0x3C) e_f16 = 1;
        if ((p & 3) != 0 && v != 0) e_u8 = 1;
    }
    if (e_f64) atomicOr(&mev[5], 1);
    if (e_bf)  atomicOr(&mev[3], 1);
    if (e_f32) atomicOr(&mev[2], 1);
    if (e_f16) atomicOr(&mev[4], 1);
    if (e_u8)  atomicOr(&mev[1], 1);
    __syncthreads();
    const int f32flag = (cnt >= 8) ? 1 : 0;
    const int mm = mev[5] ? 5 : (mev[3] ? 3 : (mev[2] ? 2 : (mev[4] ? 4 : (mev[1] ? 1 : 0))));
    if (t == 0) { flags[0] = f32flag; flags[2] = mm; }
    for (int j = t; j < B_ * S_; j += 256) {
        int m;
        if (mm == 5)      m = (((const double*)mask)[j] != 0.0);
        else if (mm == 3 || mm == 4) m = (((const unsigned short*)mask)[j] != 0);
        else if (mm == 2) m = (((const float*)mask)[j] != 0.f);
        else if (mm == 1) m = (mb[j] != 0);
        else              m = (((const int*)mask)[j] != 0);
        mflag[j] = m ? 1.f : 0.f;
    }
}

// ---------------- MFMA GEMM: QKV fused (z picks W/bias/out), bf16 out [B,H,S,d] ----------------
// 128x128 tile, BK=32, 4 waves x (64x64 = 4x4 frags of 16x16x32).
__global__ __launch_bounds__(256) void gemm_qkv_mfma(const void* __restrict__ X,
                                                     const void* __restrict__ W0,
                                                     const void* __restrict__ W1,
                                                     const void* __restrict__ W2,
                                                     const void* __restrict__ b0,
                                                     const void* __restrict__ b1,
                                                     const void* __restrict__ b2,
                                                     const int* __restrict__ flags,
                                                     unsigned short* __restrict__ q,
                                                     unsigned short* __restrict__ kk_,
                                                     unsigned short* __restrict__ v) {
    __shared__ unsigned short Asl[128][40];
    __shared__ unsigned short Bsl[128][40];
    const int f32u = flags[0];
    const int z = blockIdx.z;
    const void* W = z == 0 ? W0 : (z == 1 ? W1 : W2);
    const void* bias = z == 0 ? b0 : (z == 1 ? b1 : b2);
    unsigned short* outp = z == 0 ? q : (z == 1 ? kk_ : v);
    const int m0 = blockIdx.y * 128, n0 = blockIdx.x * 128;
    const int t = threadIdx.x;
    const int w = t >> 6, lane = t & 63;
    const int wr = w >> 1, wc = w & 1;
    const int lm = lane & 15, lg = lane >> 4;

    f32x4 acc[4][4] = {};

    for (int k0 = 0; k0 < 1024; k0 += 32) {
        // stage A: thread t -> row m=t>>1, half-row of 16 bf16
        {
            int m = t >> 1, half = t & 1;
            int base = (m0 + m) * 1024 + k0 + half * 16;
            ushort4* dst = (ushort4*)&Asl[m][half * 16];
#pragma unroll
            for (int u = 0; u < 4; ++u) {
                float4 av = ldf4(X, base + 4 * u, f32u);
                ushort4 uv = {f2b(av.x), f2b(av.y), f2b(av.z), f2b(av.w)};
                dst[u] = uv;
            }
        }
        // stage B^T: thread t -> col n=t&127, 16 consecutive k
        {
            int n = t & 127, kq = (t >> 7) * 16;
#pragma unroll
            for (int qi = 0; qi < 16; qi += 2) {
                float x0 = ldf(W, (k0 + kq + qi) * 1024 + n0 + n, f32u);
                float x1 = ldf(W, (k0 + kq + qi + 1) * 1024 + n0 + n, f32u);
                unsigned int pk = (unsigned int)f2b(x0) | ((unsigned int)f2b(x1) << 16);
                *(unsigned int*)&Bsl[n][kq + qi] = pk;
            }
        }
        __syncthreads();
        bf16x8 af[4], bfr[4];
#pragma unroll
        for (int mi = 0; mi < 4; ++mi)
            af[mi] = *(const bf16x8*)&Asl[wr * 64 + mi * 16 + lm][lg * 8];
#pragma unroll
        for (int nj = 0; nj < 4; ++nj)
            bfr[nj] = *(const bf16x8*)&Bsl[wc * 64 + nj * 16 + lm][lg * 8];
#pragma unroll
        for (int mi = 0; mi < 4; ++mi)
#pragma unroll
            for (int nj = 0; nj < 4; ++nj)
                acc[mi][nj] = __builtin_amdgcn_mfma_f32_16x16x32_bf16(af[mi], bfr[nj],
                                                                      acc[mi][nj], 0, 0, 0);
        __syncthreads();
    }
    // epilogue: C[m][n] + bias[n], permute to [B,H,S,d] bf16
#pragma unroll
    for (int nj = 0; nj < 4; ++nj) {
        int n = n0 + wc * 64 + nj * 16 + lm;
        float bv = ldf(bias, n, f32u);
        int hh = n >> 6, dd = n & 63;
#pragma unroll
        for (int mi = 0; mi < 4; ++mi) {
#pragma unroll
            for (int r = 0; r < 4; ++r) {
                int m = m0 + wr * 64 + mi * 16 + lg * 4 + r;
                int bb = m >> 10, ii = m & 1023;
                outp[((bb * H_ + hh) * S_ + ii) * DH + dd] = f2b(acc[mi][nj][r] + bv);
            }
        }
    }
}

// ---------------- MFMA GEMM: ctx(bf16) @ Wo + bo -> f32 d_out ----------------
__global__ __launch_bounds__(256) void gemm_out_mfma(const unsigned short* __restrict__ X,
                                                     const void* __restrict__ W,
                                                     const void* __restrict__ bias,
                                                     const int* __restrict__ flags,
                                                     float* __restrict__ out) {
    __shared__ unsigned short Asl[128][40];
    __shared__ unsigned short Bsl[128][40];
    const int f32u = flags[0];
    const int m0 = blockIdx.y * 128, n0 = blockIdx.x * 128;
    const int t = threadIdx.x;
    const int w = t >> 6, lane = t & 63;
    const int wr = w >> 1, wc = w & 1;
    const int lm = lane & 15, lg = lane >> 4;

    f32x4 acc[4][4] = {};

    for (int k0 = 0; k0 < 1024; k0 += 32) {
        {
            int m = t >> 1, half = t & 1;
            const ushort4* src = (const ushort4*)&X[(m0 + m) * 1024 + k0 + half * 16];
            ushort4* dst = (ushort4*)&Asl[m][half * 16];
#pragma unroll
            for (int u = 0; u < 4; ++u) dst[u] = src[u];
        }
        {
            int n = t & 127, kq = (t >> 7) * 16;
#pragma unroll
            for (int qi = 0; qi < 16; qi += 2) {
                float x0 = ldf(W, (k0 + kq + qi) * 1024 + n0 + n, f32u);
                float x1 = ldf(W, (k0 + kq + qi + 1) * 1024 + n0 + n, f32u);
                unsigned int pk = (unsigned int)f2b(x0) | ((unsigned int)f2b(x1) << 16);
                *(unsigned int*)&Bsl[n][kq + qi] = pk;
            }
        }
        __syncthreads();
        bf16x8 af[4], bfr[4];
#pragma unroll
        for (int mi = 0; mi < 4; ++mi)
            af[mi] = *(const bf16x8*)&Asl[wr * 64 + mi * 16 + lm][lg * 8];
#pragma unroll
        for (int nj = 0; nj < 4; ++nj)
            bfr[nj] = *(const bf16x8*)&Bsl[wc * 64 + nj * 16 + lm][lg * 8];
#pragma unroll
        for (int mi = 0; mi < 4; ++mi)
#pragma unroll
            for (int nj = 0; nj < 4; ++nj)
                acc[mi][nj] = __builtin_amdgcn_mfma_f32_16x16x32_bf16(af[mi], bfr[nj],
                                                                      acc[mi][nj], 0, 0, 0);
        __syncthreads();
    }
#pragma unroll
    for (int nj = 0; nj < 4; ++nj) {
        int n = n0 + wc * 64 + nj * 16 + lm;
        float bv = ldf(bias, n, f32u);
#pragma unroll
        for (int mi = 0; mi < 4; ++mi) {
#pragma unroll
            for (int r = 0; r < 4; ++r) {
                int m = m0 + wr * 64 + mi * 16 + lg * 4 + r;
                out[m * 1024 + n] = acc[mi][nj][r] + bv;
            }
        }
    }
}

// ---------------- raw_p2c (bf16 in/out) ----------------
__global__ __launch_bounds__(256) void rel_p2c(const unsigned short* __restrict__ kws,
                                               const void* __restrict__ relq,
                                               const int* __restrict__ flags,
                                               unsigned short* __restrict__ p2c) {
    __shared__ float kt[64][68];
    __shared__ float rq[33][68];
    const int f32u = flags[0];
    const int bh = blockIdx.y, h = bh & 15;
    const int j0 = blockIdx.x * 64;
    const int t = threadIdx.x;
#pragma unroll
    for (int qq = 0; qq < 4; ++qq) {
        int idx = t + 256 * qq;
        int j = idx >> 4, d4 = idx & 15;
        *(float4*)&kt[j][d4 * 4] = ldb4(kws, (bh * S_ + j0 + j) * DH + d4 * 4);
    }
    for (int idx = t; idx < 33 * 16; idx += 256) {
        int k = idx >> 4, d4 = idx & 15;
        *(float4*)&rq[k][d4 * 4] = ldf4(relq, (h * K_ + k) * DH + d4 * 4, f32u);
    }
    __syncthreads();
    for (int o = t; o < 33 * 64; o += 256) {
        int k = o >> 6, j = o & 63;
        float s = 0.f;
#pragma unroll
        for (int d4 = 0; d4 < 16; ++d4) {
            float4 a = *(const float4*)&rq[k][d4 * 4];
            float4 b = *(const float4*)&kt[j][d4 * 4];
            s += a.x * b.x + a.y * b.y + a.z * b.z + a.w * b.w;
        }
        p2c[(bh * K_ + k) * S_ + j0 + j] = f2b(s * SCALE);
    }
}

// ---------------- raw_c2p (bf16 in/out) ----------------
__global__ __launch_bounds__(256) void rel_c2p(const unsigned short* __restrict__ qws,
                                               const void* __restrict__ relk,
                                               const int* __restrict__ flags,
                                               unsigned short* __restrict__ c2p) {
    __shared__ float qt[64][68];
    __shared__ float rk[33][68];
    const int f32u = flags[0];
    const int bh = blockIdx.y, h = bh & 15;
    const int i0 = blockIdx.x * 64;
    const int t = threadIdx.x;
#pragma unroll
    for (int qq = 0; qq < 4; ++qq) {
        int idx = t + 256 * qq;
        int i = idx >> 4, d4 = idx & 15;
        *(float4*)&qt[i][d4 * 4] = ldb4(qws, (bh * S_ + i0 + i) * DH + d4 * 4);
    }
    for (int idx = t; idx < 33 * 16; idx += 256) {
        int k = idx >> 4, d4 = idx & 15;
        *(float4*)&rk[k][d4 * 4] = ldf4(relk, (h * K_ + k) * DH + d4 * 4, f32u);
    }
    __syncthreads();
    for (int o = t; o < 64 * 33; o += 256) {
        int i = o / 33, k = o % 33;
        float s = 0.f;
#pragma unroll
        for (int d4 = 0; d4 < 16; ++d4) {
            float4 a = *(const float4*)&qt[i][d4 * 4];
            float4 b = *(const float4*)&rk[k][d4 * 4];
            s += a.x * b.x + a.y * b.y + a.z * b.z + a.w * b.w;
        }
        c2p[(bh * S_ + i0 + i) * K_ + k] = f2b(s * SCALE);
    }
}

// ---------------- two-pass attention (bf16 staged inputs), f32 math ----------------
__global__ __launch_bounds__(256) void attn_simple(const unsigned short* __restrict__ qws,
                                                   const unsigned short* __restrict__ kws,
                                                   const unsigned short* __restrict__ vws,
                                                   const unsigned short* __restrict__ p2c,
                                                   const unsigned short* __restrict__ c2p,
                                                   const float* __restrict__ mflag,
                                                   const int* __restrict__ pos,
                                                   const void* __restrict__ relv,
                                                   const int* __restrict__ flags,
                                                   unsigned short* __restrict__ ctxo) {
    __shared__ float Ssc[8][1024];
    __shared__ float kt[64][68];
    __shared__ float rvt[33][64];
    __shared__ float qs[8][68];
    __shared__ float c2ps[8][34];
    __shared__ float ag[8][34];

    const int f32u = flags[0];
    const int bh = blockIdx.y, b = bh >> 4, h = bh & 15;
    const int i0 = blockIdx.x * 8;
    const int t = threadIdx.x;
    const int ti = t >> 5;
    const int tw = t & 31;
    const int irow = i0 + ti;

    for (int idx = t; idx < 8 * 16; idx += 256) {
        int i = idx >> 4, d4 = idx & 15;
        *(float4*)&qs[i][d4 * 4] = ldb4(qws, (bh * S_ + i0 + i) * DH + d4 * 4);
    }
    for (int idx = t; idx < 8 * 33; idx += 256) {
        int i = idx / 33, k = idx % 33;
        c2ps[i][k] = b2f(c2p[(bh * S_ + i0 + i) * K_ + k]);
    }
    for (int idx = t; idx < 8 * 34; idx += 256) ag[idx / 34][idx % 34] = 0.f;

    // phase 1: scores
    for (int jt = 0; jt < 16; ++jt) {
        const int j0 = jt * 64;
        __syncthreads();
#pragma unroll
        for (int qq = 0; qq < 4; ++qq) {
            int idx = t + 256 * qq;
            int j = idx >> 4, d4 = idx & 15;
            *(float4*)&kt[j][d4 * 4] = ldb4(kws, (bh * S_ + j0 + j) * DH + d4 * 4);
        }
        for (int idx = t; idx < 33 * 16; idx += 256) {
            int k = idx >> 4, j4 = idx & 15;
            *(float4*)&rvt[k][j4 * 4] = ldb4(p2c, (bh * K_ + k) * S_ + j0 + j4 * 4);
        }
        __syncthreads();
        for (int idx = t; idx < 8 * 64; idx += 256) {
            int i = idx >> 6, j = idx & 63;
            float s = 0.f;
#pragma unroll
            for (int d4 = 0; d4 < 16; ++d4) {
                float4 a = *(const float4*)&qs[i][d4 * 4];
                float4 kv = *(const float4*)&kt[j][d4 * 4];
                s += a.x * kv.x + a.y * kv.y + a.z * kv.z + a.w * kv.w;
            }
            s *= SCALE;
            int pb = pos[(b * S_ + i0 + i) * S_ + j0 + j];
            pb = min(max(pb, 0), K_ - 1);
            s += rvt[pb][j] + c2ps[i][pb];
            if (mflag[b * S_ + j0 + j] != 0.f) s = -1e9f;
            Ssc[i][j0 + j] = s;
        }
    }
    __syncthreads();

    // phase 2: row softmax (unnormalized)
    float m = -1e30f;
    for (int j = tw; j < 1024; j += 32) m = fmaxf(m, Ssc[ti][j]);
#pragma unroll
    for (int off = 1; off < 32; off <<= 1) m = fmaxf(m, __shfl_xor(m, off));
    float sum = 0.f;
    for (int j = tw; j < 1024; j += 32) {
        float e = __expf(Ssc[ti][j] - m);
        Ssc[ti][j] = e;
        sum += e;
    }
#pragma unroll
    for (int off = 1; off < 32; off <<= 1) sum += __shfl_xor(sum, off);
    __syncthreads();

    // phase 3: bucket aggregation
    for (int j = tw; j < 1024; j += 32) {
        int pb = pos[(b * S_ + irow) * S_ + j];
        pb = min(max(pb, 0), K_ - 1);
        atomicAdd(&ag[ti][pb], Ssc[ti][j]);
    }

    // phase 4: ctx = P @ V
    const int d0 = tw * 2;
    float acc0 = 0.f, acc1 = 0.f;
    for (int jt = 0; jt < 16; ++jt) {
        const int j0 = jt * 64;
        __syncthreads();
#pragma unroll
        for (int qq = 0; qq < 4; ++qq) {
            int idx = t + 256 * qq;
            int j = idx >> 4, d4 = idx & 15;
            *(float4*)&kt[j][d4 * 4] = ldb4(vws, (bh * S_ + j0 + j) * DH + d4 * 4);
        }
        __syncthreads();
        for (int j = 0; j < 64; ++j) {
            float p = Ssc[ti][j0 + j];
            acc0 += p * kt[j][d0];
            acc1 += p * kt[j][d0 + 1];
        }
    }

    // phase 5: + agg @ rel_v, normalize, write bf16 ctx
    __syncthreads();
    for (int idx = t; idx < 33 * 16; idx += 256) {
        int k = idx >> 4, d4 = idx & 15;
        *(float4*)&rvt[k][d4 * 4] = ldf4(relv, (h * K_ + k) * DH + d4 * 4, f32u);
    }
    __syncthreads();
    for (int kb = 0; kb < 33; ++kb) {
        float a = ag[ti][kb];
        acc0 += a * rvt[kb][d0];
        acc1 += a * rvt[kb][d0 + 1];
    }
    float inv = 1.0f / sum;
    ctxo[(b * S_ + irow) * D_ + h * DH + d0] = f2b(acc0 * inv);
    ctxo[(b * S_ + irow) * D_ + h * DH + d0 + 1] = f2b(acc1 * inv);
}

// ---------------- launcher ----------------
extern "C" void kernel_launch(void* const* d_in, const int* in_sizes, int n_in,
                              void* d_out, int out_size, void* d_ws, size_t ws_size,
                              hipStream_t stream) {
    const void* hidden = d_in[0];
    const void* pos = d_in[1];
    const void* mask = d_in[2];
    const void* Wq = d_in[3];
    const void* bq = d_in[4];
    const void* Wk = d_in[5];
    const void* bk = d_in[6];
    const void* Wv = d_in[7];
    const void* bv = d_in[8];
    const void* Wo = d_in[9];
    const void* bo = d_in[10];
    const void* rq = d_in[11];
    const void* rk = d_in[12];
    const void* rv = d_in[13];

    unsigned char* wsb = (unsigned char*)d_ws;
    size_t o = 0;
    int* flags = (int*)(wsb + o);            o += 256;
    float* mfl = (float*)(wsb + o);          o += 2048 * 4;
    o = (o + 255) & ~(size_t)255;
    unsigned short* qb   = (unsigned short*)(wsb + o); o += 4194304;
    unsigned short* kb   = (unsigned short*)(wsb + o); o += 4194304;
    unsigned short* vb   = (unsigned short*)(wsb + o); o += 4194304;
    unsigned short* p2cb = (unsigned short*)(wsb + o); o += 2162688;
    unsigned short* c2pb = (unsigned short*)(wsb + o); o += 2162688;
    unsigned short* ctxb = (unsigned short*)(wsb + o); o += 4194304;  // ~21.1 MB total

    float* out = (float*)d_out;
    const int* posi = (const int*)pos;

    dim3 tb(256);
    prep<<<dim3(1), tb, 0, stream>>>(hidden, mask, flags, mfl);
    gemm_qkv_mfma<<<dim3(8, 16, 3), tb, 0, stream>>>(hidden, Wq, Wk, Wv, bq, bk, bv,
                                                     flags, qb, kb, vb);
    rel_p2c<<<dim3(16, 32), tb, 0, stream>>>(kb, rq, flags, p2cb);
    rel_c2p<<<dim3(16, 32), tb, 0, stream>>>(qb, rk, flags, c2pb);
    attn_simple<<<dim3(128, 32), tb, 0, stream>>>(qb, kb, vb, p2cb, c2pb, mfl, posi, rv,
                                                  flags, ctxb);
    gemm_out_mfma<<<dim3(8, 16), tb, 0, stream>>>(ctxb, Wo, bo, flags, out);
}

// Round 7
// 473.724 us; speedup vs baseline: 2.9011x; 2.0179x over previous
//
#include <hip/hip_runtime.h>
#include <hip/hip_bf16.h>

#define B_ 2
#define S_ 1024
#define D_ 1024
#define H_ 16
#define K_ 33
#define DH 64
#define SCALE 0.07216878364870322f  // 1/sqrt(3*64)

typedef __attribute__((ext_vector_type(8))) short bf16x8;
typedef __attribute__((ext_vector_type(4))) float f32x4;

// ---------- dtype helpers ----------
__device__ __forceinline__ float b2f(unsigned short u) {
    return __uint_as_float(((unsigned int)u) << 16);
}
__device__ __forceinline__ unsigned short f2b(float f) {  // RNE
    unsigned int u = __float_as_uint(f);
    u += 0x7FFFu + ((u >> 16) & 1u);
    return (unsigned short)(u >> 16);
}
__device__ __forceinline__ float ldf(const void* p, int i, int f32) {
    return f32 ? ((const float*)p)[i] : b2f(((const unsigned short*)p)[i]);
}
__device__ __forceinline__ float4 ldf4(const void* p, int i, int f32) {  // i % 4 == 0
    if (f32) return *(const float4*)((const float*)p + i);
    ushort4 u = *(const ushort4*)((const unsigned short*)p + i);
    return make_float4(b2f(u.x), b2f(u.y), b2f(u.z), b2f(u.w));
}
__device__ __forceinline__ float4 ldb4(const unsigned short* p, int i) {  // bf16 buffer
    ushort4 u = *(const ushort4*)(p + i);
    return make_float4(b2f(u.x), b2f(u.y), b2f(u.z), b2f(u.w));
}

// ---------------- prep: sniff dtypes, build mflag ----------------
__global__ __launch_bounds__(256) void prep(const void* __restrict__ hidden,
                                            const void* __restrict__ mask,
                                            int* __restrict__ flags,
                                            float* __restrict__ mflag) {
    __shared__ int cnt;
    __shared__ int mev[6];
    const int t = threadIdx.x;
    if (t == 0) cnt = 0;
    if (t < 6) mev[t] = 0;
    __syncthreads();
    const unsigned short* hu = (const unsigned short*)hidden;
    int c = 0;
    for (int i = t; i < 2048; i += 256) {
        int e = (hu[i] >> 7) & 0xFF;
        if (e >= 0x8E) c++;
    }
    if (c) atomicAdd(&cnt, c);
    const unsigned char* mb = (const unsigned char*)mask;
    int e_bf = 0, e_f32 = 0, e_f64 = 0, e_f16 = 0, e_u8 = 0;
    for (int p = t; p < 2048; p += 256) {
        unsigned char v = mb[p];
        if ((p & 7) == 6 && v == 0xF0) e_f64 = 1;
        if ((p & 3) == 1 && v == 0x3F) e_bf = 1;
        if ((p & 3) == 3 && v == 0x3F) e_f32 = 1;
        if ((p & 1) == 1 && v == 0x3C) e_f16 = 1;
        if ((p & 3) != 0 && v != 0) e_u8 = 1;
    }
    if (e_f64) atomicOr(&mev[5], 1);
    if (e_bf)  atomicOr(&mev[3], 1);
    if (e_f32) atomicOr(&mev[2], 1);
    if (e_f16) atomicOr(&mev[4], 1);
    if (e_u8)  atomicOr(&mev[1], 1);
    __syncthreads();
    const int f32flag = (cnt >= 8) ? 1 : 0;
    const int mm = mev[5] ? 5 : (mev[3] ? 3 : (mev[2] ? 2 : (mev[4] ? 4 : (mev[1] ? 1 : 0))));
    if (t == 0) { flags[0] = f32flag; flags[2] = mm; }
    for (int j = t; j < B_ * S_; j += 256) {
        int m;
        if (mm == 5)      m = (((const double*)mask)[j] != 0.0);
        else if (mm == 3 || mm == 4) m = (((const unsigned short*)mask)[j] != 0);
        else if (mm == 2) m = (((const float*)mask)[j] != 0.f);
        else if (mm == 1) m = (mb[j] != 0);
        else              m = (((const int*)mask)[j] != 0);
        mflag[j] = m ? 1.f : 0.f;
    }
}

// ---------------- MFMA GEMM: QKV fused (z picks W/bias/out), bf16 out [B,H,S,d] ----------------
__global__ __launch_bounds__(256) void gemm_qkv_mfma(const void* __restrict__ X,
                                                     const void* __restrict__ W0,
                                                     const void* __restrict__ W1,
                                                     const void* __restrict__ W2,
                                                     const void* __restrict__ b0,
                                                     const void* __restrict__ b1,
                                                     const void* __restrict__ b2,
                                                     const int* __restrict__ flags,
                                                     unsigned short* __restrict__ q,
                                                     unsigned short* __restrict__ kk_,
                                                     unsigned short* __restrict__ v) {
    __shared__ unsigned short Asl[128][40];
    __shared__ unsigned short Bsl[128][40];
    const int f32u = flags[0];
    const int z = blockIdx.z;
    const void* W = z == 0 ? W0 : (z == 1 ? W1 : W2);
    const void* bias = z == 0 ? b0 : (z == 1 ? b1 : b2);
    unsigned short* outp = z == 0 ? q : (z == 1 ? kk_ : v);
    const int m0 = blockIdx.y * 128, n0 = blockIdx.x * 128;
    const int t = threadIdx.x;
    const int w = t >> 6, lane = t & 63;
    const int wr = w >> 1, wc = w & 1;
    const int lm = lane & 15, lg = lane >> 4;

    f32x4 acc[4][4] = {};

    for (int k0 = 0; k0 < 1024; k0 += 32) {
        {
            int m = t >> 1, half = t & 1;
            int base = (m0 + m) * 1024 + k0 + half * 16;
            ushort4* dst = (ushort4*)&Asl[m][half * 16];
#pragma unroll
            for (int u = 0; u < 4; ++u) {
                float4 av = ldf4(X, base + 4 * u, f32u);
                ushort4 uv = {f2b(av.x), f2b(av.y), f2b(av.z), f2b(av.w)};
                dst[u] = uv;
            }
        }
        {
            int n = t & 127, kq = (t >> 7) * 16;
#pragma unroll
            for (int qi = 0; qi < 16; qi += 2) {
                float x0 = ldf(W, (k0 + kq + qi) * 1024 + n0 + n, f32u);
                float x1 = ldf(W, (k0 + kq + qi + 1) * 1024 + n0 + n, f32u);
                unsigned int pk = (unsigned int)f2b(x0) | ((unsigned int)f2b(x1) << 16);
                *(unsigned int*)&Bsl[n][kq + qi] = pk;
            }
        }
        __syncthreads();
        bf16x8 af[4], bfr[4];
#pragma unroll
        for (int mi = 0; mi < 4; ++mi)
            af[mi] = *(const bf16x8*)&Asl[wr * 64 + mi * 16 + lm][lg * 8];
#pragma unroll
        for (int nj = 0; nj < 4; ++nj)
            bfr[nj] = *(const bf16x8*)&Bsl[wc * 64 + nj * 16 + lm][lg * 8];
#pragma unroll
        for (int mi = 0; mi < 4; ++mi)
#pragma unroll
            for (int nj = 0; nj < 4; ++nj)
                acc[mi][nj] = __builtin_amdgcn_mfma_f32_16x16x32_bf16(af[mi], bfr[nj],
                                                                      acc[mi][nj], 0, 0, 0);
        __syncthreads();
    }
#pragma unroll
    for (int nj = 0; nj < 4; ++nj) {
        int n = n0 + wc * 64 + nj * 16 + lm;
        float bv = ldf(bias, n, f32u);
        int hh = n >> 6, dd = n & 63;
#pragma unroll
        for (int mi = 0; mi < 4; ++mi) {
#pragma unroll
            for (int r = 0; r < 4; ++r) {
                int m = m0 + wr * 64 + mi * 16 + lg * 4 + r;
                int bb = m >> 10, ii = m & 1023;
                outp[((bb * H_ + hh) * S_ + ii) * DH + dd] = f2b(acc[mi][nj][r] + bv);
            }
        }
    }
}

// ---------------- MFMA GEMM: ctx(bf16) @ Wo + bo -> f32 d_out ----------------
__global__ __launch_bounds__(256) void gemm_out_mfma(const unsigned short* __restrict__ X,
                                                     const void* __restrict__ W,
                                                     const void* __restrict__ bias,
                                                     const int* __restrict__ flags,
                                                     float* __restrict__ out) {
    __shared__ unsigned short Asl[128][40];
    __shared__ unsigned short Bsl[128][40];
    const int f32u = flags[0];
    const int m0 = blockIdx.y * 128, n0 = blockIdx.x * 128;
    const int t = threadIdx.x;
    const int w = t >> 6, lane = t & 63;
    const int wr = w >> 1, wc = w & 1;
    const int lm = lane & 15, lg = lane >> 4;

    f32x4 acc[4][4] = {};

    for (int k0 = 0; k0 < 1024; k0 += 32) {
        {
            int m = t >> 1, half = t & 1;
            const ushort4* src = (const ushort4*)&X[(m0 + m) * 1024 + k0 + half * 16];
            ushort4* dst = (ushort4*)&Asl[m][half * 16];
#pragma unroll
            for (int u = 0; u < 4; ++u) dst[u] = src[u];
        }
        {
            int n = t & 127, kq = (t >> 7) * 16;
#pragma unroll
            for (int qi = 0; qi < 16; qi += 2) {
                float x0 = ldf(W, (k0 + kq + qi) * 1024 + n0 + n, f32u);
                float x1 = ldf(W, (k0 + kq + qi + 1) * 1024 + n0 + n, f32u);
                unsigned int pk = (unsigned int)f2b(x0) | ((unsigned int)f2b(x1) << 16);
                *(unsigned int*)&Bsl[n][kq + qi] = pk;
            }
        }
        __syncthreads();
        bf16x8 af[4], bfr[4];
#pragma unroll
        for (int mi = 0; mi < 4; ++mi)
            af[mi] = *(const bf16x8*)&Asl[wr * 64 + mi * 16 + lm][lg * 8];
#pragma unroll
        for (int nj = 0; nj < 4; ++nj)
            bfr[nj] = *(const bf16x8*)&Bsl[wc * 64 + nj * 16 + lm][lg * 8];
#pragma unroll
        for (int mi = 0; mi < 4; ++mi)
#pragma unroll
            for (int nj = 0; nj < 4; ++nj)
                acc[mi][nj] = __builtin_amdgcn_mfma_f32_16x16x32_bf16(af[mi], bfr[nj],
                                                                      acc[mi][nj], 0, 0, 0);
        __syncthreads();
    }
#pragma unroll
    for (int nj = 0; nj < 4; ++nj) {
        int n = n0 + wc * 64 + nj * 16 + lm;
        float bv = ldf(bias, n, f32u);
#pragma unroll
        for (int mi = 0; mi < 4; ++mi) {
#pragma unroll
            for (int r = 0; r < 4; ++r) {
                int m = m0 + wr * 64 + mi * 16 + lg * 4 + r;
                out[m * 1024 + n] = acc[mi][nj][r] + bv;
            }
        }
    }
}

// ---------------- raw_p2c (bf16 in/out) ----------------
__global__ __launch_bounds__(256) void rel_p2c(const unsigned short* __restrict__ kws,
                                               const void* __restrict__ relq,
                                               const int* __restrict__ flags,
                                               unsigned short* __restrict__ p2c) {
    __shared__ float kt[64][68];
    __shared__ float rq[33][68];
    const int f32u = flags[0];
    const int bh = blockIdx.y, h = bh & 15;
    const int j0 = blockIdx.x * 64;
    const int t = threadIdx.x;
#pragma unroll
    for (int qq = 0; qq < 4; ++qq) {
        int idx = t + 256 * qq;
        int j = idx >> 4, d4 = idx & 15;
        *(float4*)&kt[j][d4 * 4] = ldb4(kws, (bh * S_ + j0 + j) * DH + d4 * 4);
    }
    for (int idx = t; idx < 33 * 16; idx += 256) {
        int k = idx >> 4, d4 = idx & 15;
        *(float4*)&rq[k][d4 * 4] = ldf4(relq, (h * K_ + k) * DH + d4 * 4, f32u);
    }
    __syncthreads();
    for (int o = t; o < 33 * 64; o += 256) {
        int k = o >> 6, j = o & 63;
        float s = 0.f;
#pragma unroll
        for (int d4 = 0; d4 < 16; ++d4) {
            float4 a = *(const float4*)&rq[k][d4 * 4];
            float4 b = *(const float4*)&kt[j][d4 * 4];
            s += a.x * b.x + a.y * b.y + a.z * b.z + a.w * b.w;
        }
        p2c[(bh * K_ + k) * S_ + j0 + j] = f2b(s * SCALE);
    }
}

// ---------------- raw_c2p (bf16 in/out) ----------------
__global__ __launch_bounds__(256) void rel_c2p(const unsigned short* __restrict__ qws,
                                               const void* __restrict__ relk,
                                               const int* __restrict__ flags,
                                               unsigned short* __restrict__ c2p) {
    __shared__ float qt[64][68];
    __shared__ float rk[33][68];
    const int f32u = flags[0];
    const int bh = blockIdx.y, h = bh & 15;
    const int i0 = blockIdx.x * 64;
    const int t = threadIdx.x;
#pragma unroll
    for (int qq = 0; qq < 4; ++qq) {
        int idx = t + 256 * qq;
        int i = idx >> 4, d4 = idx & 15;
        *(float4*)&qt[i][d4 * 4] = ldb4(qws, (bh * S_ + i0 + i) * DH + d4 * 4);
    }
    for (int idx = t; idx < 33 * 16; idx += 256) {
        int k = idx >> 4, d4 = idx & 15;
        *(float4*)&rk[k][d4 * 4] = ldf4(relk, (h * K_ + k) * DH + d4 * 4, f32u);
    }
    __syncthreads();
    for (int o = t; o < 64 * 33; o += 256) {
        int i = o / 33, k = o % 33;
        float s = 0.f;
#pragma unroll
        for (int d4 = 0; d4 < 16; ++d4) {
            float4 a = *(const float4*)&qt[i][d4 * 4];
            float4 b = *(const float4*)&rk[k][d4 * 4];
            s += a.x * b.x + a.y * b.y + a.z * b.z + a.w * b.w;
        }
        c2p[(bh * S_ + i0 + i) * K_ + k] = f2b(s * SCALE);
    }
}

// ---------------- MFMA attention ----------------
// Block: 512 thr = 8 waves, 64 q-rows of one (b,h). Dynamic LDS:
//   Ps   [64][1024] bf16, XOR-swizzled rows (128 KB)
//   VT   [64][72]   bf16 (V^T chunk, 9216 B)
//   c2pS [64][34]   bf16; agS [64][34] f32; rvS [33][64] bf16; mflagS u8[1024]; rowsumS f32[64]
#define PS_OFF   0
#define VT_OFF   131072
#define C2P_OFF  140288
#define AG_OFF   144640
#define RV_OFF   153344
#define MF_OFF   157568
#define RS_OFF   158592
#define ATTN_LDS 158848

__device__ __forceinline__ int ps_addr(int il, int j) {
    return PS_OFF + il * 2048 + ((j * 2) ^ ((il & 7) << 4));
}

__global__ __launch_bounds__(512, 2) void attn_mfma(const unsigned short* __restrict__ qws,
                                                    const unsigned short* __restrict__ kws,
                                                    const unsigned short* __restrict__ vws,
                                                    const unsigned short* __restrict__ p2c,
                                                    const unsigned short* __restrict__ c2p,
                                                    const float* __restrict__ mflag,
                                                    const int* __restrict__ pos,
                                                    const void* __restrict__ relv,
                                                    const int* __restrict__ flags,
                                                    unsigned short* __restrict__ ctxo) {
    extern __shared__ char smem[];
    const int f32u = flags[0];
    const int bh = blockIdx.y, b = bh >> 4, h = bh & 15;
    const int i0 = blockIdx.x * 64;
    const int t = threadIdx.x;
    const int w = t >> 6, lane = t & 63;
    const int lm = lane & 15, lg = lane >> 4;
    const int iband = (w & 3) * 16;     // wave's 16-row i-band (phases 1 & 3)
    const int jh = w >> 2;              // wave's j-half in phase 1

    float* agS = (float*)(smem + AG_OFF);
    float* rowsumS = (float*)(smem + RS_OFF);
    unsigned short* c2pS = (unsigned short*)(smem + C2P_OFF);
    unsigned short* rvS = (unsigned short*)(smem + RV_OFF);
    unsigned char* mfS = (unsigned char*)(smem + MF_OFF);

    // ---- phase 0: stage small tables ----
    for (int idx = t; idx < 64 * 33; idx += 512) {
        int il = idx / 33, k = idx % 33;
        c2pS[il * 34 + k] = c2p[(bh * S_ + i0 + il) * K_ + k];
    }
    for (int idx = t; idx < 33 * 64; idx += 512) {
        int k = idx >> 6, d = idx & 63;
        rvS[k * 64 + d] = f2b(ldf(relv, (h * K_ + k) * DH + d, f32u));
    }
    for (int idx = t; idx < 1024; idx += 512)
        mfS[idx] = (mflag[b * S_ + idx] != 0.f) ? 1 : 0;
    for (int idx = t; idx < 64 * 34; idx += 512) agS[idx] = 0.f;
    __syncthreads();

    // ---- phase 1: QK^T (MFMA) + gathers + exp + strip write + agg atomics ----
    bf16x8 aq0 = *(const bf16x8*)&qws[(bh * S_ + i0 + iband + lm) * DH + lg * 8];
    bf16x8 aq1 = *(const bf16x8*)&qws[(bh * S_ + i0 + iband + lm) * DH + 32 + lg * 8];
    for (int jt = 0; jt < 32; ++jt) {
        const int j0 = jh * 512 + jt * 16;
        bf16x8 kf0 = *(const bf16x8*)&kws[(bh * S_ + j0 + lm) * DH + lg * 8];
        bf16x8 kf1 = *(const bf16x8*)&kws[(bh * S_ + j0 + lm) * DH + 32 + lg * 8];
        f32x4 a = {};
        a = __builtin_amdgcn_mfma_f32_16x16x32_bf16(aq0, kf0, a, 0, 0, 0);
        a = __builtin_amdgcn_mfma_f32_16x16x32_bf16(aq1, kf1, a, 0, 0, 0);
        const int jcol = j0 + lm;
        const int masked = mfS[jcol];
        const int posrow = (b * S_) * S_ + jcol;
#pragma unroll
        for (int r = 0; r < 4; ++r) {
            int il = iband + lg * 4 + r;
            int i = i0 + il;
            float s = a[r] * SCALE;
            int pb = pos[posrow + i * S_];
            pb = min(max(pb, 0), K_ - 1);
            s += b2f(p2c[(bh * K_ + pb) * S_ + jcol]) + b2f(c2pS[il * 34 + pb]);
            if (masked) s = -1e9f;
            float e = __expf(s);
            *(unsigned short*)(smem + ps_addr(il, jcol)) = f2b(e);
            atomicAdd(&agS[il * 34 + pb], e);
        }
    }
    __syncthreads();

    // ---- phase 2: row sums (max-free softmax denominator) ----
    {
        const int g = t >> 5, ln = t & 31;
#pragma unroll
        for (int rr = 0; rr < 4; ++rr) {
            int il = g * 4 + rr;
            float sm = 0.f;
            for (int j = ln; j < 1024; j += 32)
                sm += b2f(*(const unsigned short*)(smem + ps_addr(il, j)));
#pragma unroll
            for (int off = 1; off < 32; off <<= 1) sm += __shfl_xor(sm, off);
            if (ln == 0) rowsumS[il] = sm;
        }
    }
    __syncthreads();

    // ---- phase 3: PV via MFMA; V^T staged per 64-j chunk ----
    const int dbase = (w >> 2) * 32;
    f32x4 acc0 = {}, acc1 = {};
    for (int jc = 0; jc < 16; ++jc) {
        {   // stage VT[d][jj] for this chunk
            int j = jc * 64 + (t >> 3);
            int d0 = (t & 7) * 8;
            bf16x8 vv = *(const bf16x8*)&vws[(bh * S_ + j) * DH + d0];
#pragma unroll
            for (int e = 0; e < 8; ++e)
                *(unsigned short*)(smem + VT_OFF + (d0 + e) * 144 + (t >> 3) * 2) =
                    ((short*)&vv)[e];
        }
        __syncthreads();
#pragma unroll
        for (int ks = 0; ks < 2; ++ks) {
            bf16x8 af = *(const bf16x8*)(smem + ps_addr(iband + lm, jc * 64 + ks * 32 + lg * 8));
            bf16x8 b0 = *(const bf16x8*)(smem + VT_OFF + (dbase + lm) * 144 +
                                         (ks * 32 + lg * 8) * 2);
            bf16x8 b1 = *(const bf16x8*)(smem + VT_OFF + (dbase + 16 + lm) * 144 +
                                         (ks * 32 + lg * 8) * 2);
            acc0 = __builtin_amdgcn_mfma_f32_16x16x32_bf16(af, b0, acc0, 0, 0, 0);
            acc1 = __builtin_amdgcn_mfma_f32_16x16x32_bf16(af, b1, acc1, 0, 0, 0);
        }
        __syncthreads();
    }

    // ---- phase 4: + agg @ rel_v, normalize, write ctx ----
#pragma unroll
    for (int dt = 0; dt < 2; ++dt) {
        f32x4 acc = dt == 0 ? acc0 : acc1;
#pragma unroll
        for (int r = 0; r < 4; ++r) {
            int il = iband + lg * 4 + r;
            int d = dbase + dt * 16 + lm;
            float o = acc[r];
            for (int kb = 0; kb < K_; ++kb)
                o += agS[il * 34 + kb] * b2f(rvS[kb * 64 + d]);
            o *= 1.0f / rowsumS[il];
            ctxo[(b * S_ + i0 + il) * D_ + h * DH + d] = f2b(o);
        }
    }
}

// ---------------- launcher ----------------
extern "C" void kernel_launch(void* const* d_in, const int* in_sizes, int n_in,
                              void* d_out, int out_size, void* d_ws, size_t ws_size,
                              hipStream_t stream) {
    const void* hidden = d_in[0];
    const void* pos = d_in[1];
    const void* mask = d_in[2];
    const void* Wq = d_in[3];
    const void* bq = d_in[4];
    const void* Wk = d_in[5];
    const void* bk = d_in[6];
    const void* Wv = d_in[7];
    const void* bv = d_in[8];
    const void* Wo = d_in[9];
    const void* bo = d_in[10];
    const void* rq = d_in[11];
    const void* rk = d_in[12];
    const void* rv = d_in[13];

    unsigned char* wsb = (unsigned char*)d_ws;
    size_t o = 0;
    int* flags = (int*)(wsb + o);            o += 256;
    float* mfl = (float*)(wsb + o);          o += 2048 * 4;
    o = (o + 255) & ~(size_t)255;
    unsigned short* qb   = (unsigned short*)(wsb + o); o += 4194304;
    unsigned short* kb   = (unsigned short*)(wsb + o); o += 4194304;
    unsigned short* vb   = (unsigned short*)(wsb + o); o += 4194304;
    unsigned short* p2cb = (unsigned short*)(wsb + o); o += 2162688;
    unsigned short* c2pb = (unsigned short*)(wsb + o); o += 2162688;
    unsigned short* ctxb = (unsigned short*)(wsb + o); o += 4194304;  // ~21.1 MB total

    float* out = (float*)d_out;
    const int* posi = (const int*)pos;

    static int attr_set = 0;
    (void)attr_set;
    hipFuncSetAttribute(reinterpret_cast<const void*>(attn_mfma),
                        hipFuncAttributeMaxDynamicSharedMemorySize, ATTN_LDS);

    dim3 tb(256);
    prep<<<dim3(1), tb, 0, stream>>>(hidden, mask, flags, mfl);
    gemm_qkv_mfma<<<dim3(8, 16, 3), tb, 0, stream>>>(hidden, Wq, Wk, Wv, bq, bk, bv,
                                                     flags, qb, kb, vb);
    rel_p2c<<<dim3(16, 32), tb, 0, stream>>>(kb, rq, flags, p2cb);
    rel_c2p<<<dim3(16, 32), tb, 0, stream>>>(qb, rk, flags, c2pb);
    attn_mfma<<<dim3(16, 32), dim3(512), ATTN_LDS, stream>>>(qb, kb, vb, p2cb, c2pb, mfl,
                                                             posi, rv, flags, ctxb);
    gemm_out_mfma<<<dim3(8, 16), tb, 0, stream>>>(ctxb, Wo, bo, flags, out);
}

// Round 8
// 442.599 us; speedup vs baseline: 3.1051x; 1.0703x over previous
//
#include <hip/hip_runtime.h>
#include <hip/hip_bf16.h>

#define B_ 2
#define S_ 1024
#define D_ 1024
#define H_ 16
#define K_ 33
#define DH 64
#define SCALE 0.07216878364870322f  // 1/sqrt(3*64)

typedef __attribute__((ext_vector_type(8))) short bf16x8;
typedef __attribute__((ext_vector_type(4))) float f32x4;

// ---------- dtype helpers ----------
__device__ __forceinline__ float b2f(unsigned short u) {
    return __uint_as_float(((unsigned int)u) << 16);
}
__device__ __forceinline__ unsigned short f2b(float f) {  // RNE
    unsigned int u = __float_as_uint(f);
    u += 0x7FFFu + ((u >> 16) & 1u);
    return (unsigned short)(u >> 16);
}
__device__ __forceinline__ float ldf(const void* p, int i, int f32) {
    return f32 ? ((const float*)p)[i] : b2f(((const unsigned short*)p)[i]);
}
__device__ __forceinline__ float4 ldf4(const void* p, int i, int f32) {  // i % 4 == 0
    if (f32) return *(const float4*)((const float*)p + i);
    ushort4 u = *(const ushort4*)((const unsigned short*)p + i);
    return make_float4(b2f(u.x), b2f(u.y), b2f(u.z), b2f(u.w));
}
__device__ __forceinline__ float4 ldb4(const unsigned short* p, int i) {  // bf16 buffer
    ushort4 u = *(const ushort4*)(p + i);
    return make_float4(b2f(u.x), b2f(u.y), b2f(u.z), b2f(u.w));
}

// ---------------- prep: sniff dtypes, build mflag ----------------
__global__ __launch_bounds__(256) void prep(const void* __restrict__ hidden,
                                            const void* __restrict__ mask,
                                            int* __restrict__ flags,
                                            float* __restrict__ mflag) {
    __shared__ int cnt;
    __shared__ int mev[6];
    const int t = threadIdx.x;
    if (t == 0) cnt = 0;
    if (t < 6) mev[t] = 0;
    __syncthreads();
    const unsigned short* hu = (const unsigned short*)hidden;
    int c = 0;
    for (int i = t; i < 2048; i += 256) {
        int e = (hu[i] >> 7) & 0xFF;
        if (e >= 0x8E) c++;
    }
    if (c) atomicAdd(&cnt, c);
    const unsigned char* mb = (const unsigned char*)mask;
    int e_bf = 0, e_f32 = 0, e_f64 = 0, e_f16 = 0, e_u8 = 0;
    for (int p = t; p < 2048; p += 256) {
        unsigned char v = mb[p];
        if ((p & 7) == 6 && v == 0xF0) e_f64 = 1;
        if ((p & 3) == 1 && v == 0x3F) e_bf = 1;
        if ((p & 3) == 3 && v == 0x3F) e_f32 = 1;
        if ((p & 1) == 1 && v == 0x3C) e_f16 = 1;
        if ((p & 3) != 0 && v != 0) e_u8 = 1;
    }
    if (e_f64) atomicOr(&mev[5], 1);
    if (e_bf)  atomicOr(&mev[3], 1);
    if (e_f32) atomicOr(&mev[2], 1);
    if (e_f16) atomicOr(&mev[4], 1);
    if (e_u8)  atomicOr(&mev[1], 1);
    __syncthreads();
    const int f32flag = (cnt >= 8) ? 1 : 0;
    const int mm = mev[5] ? 5 : (mev[3] ? 3 : (mev[2] ? 2 : (mev[4] ? 4 : (mev[1] ? 1 : 0))));
    if (t == 0) { flags[0] = f32flag; flags[2] = mm; }
    for (int j = t; j < B_ * S_; j += 256) {
        int m;
        if (mm == 5)      m = (((const double*)mask)[j] != 0.0);
        else if (mm == 3 || mm == 4) m = (((const unsigned short*)mask)[j] != 0);
        else if (mm == 2) m = (((const float*)mask)[j] != 0.f);
        else if (mm == 1) m = (mb[j] != 0);
        else              m = (((const int*)mask)[j] != 0);
        mflag[j] = m ? 1.f : 0.f;
    }
}

// ---------------- MFMA GEMM: QKV fused (z picks W/bias/out), bf16 out [B,H,S,d] ----------------
__global__ __launch_bounds__(256) void gemm_qkv_mfma(const void* __restrict__ X,
                                                     const void* __restrict__ W0,
                                                     const void* __restrict__ W1,
                                                     const void* __restrict__ W2,
                                                     const void* __restrict__ b0,
                                                     const void* __restrict__ b1,
                                                     const void* __restrict__ b2,
                                                     const int* __restrict__ flags,
                                                     unsigned short* __restrict__ q,
                                                     unsigned short* __restrict__ kk_,
                                                     unsigned short* __restrict__ v) {
    __shared__ unsigned short Asl[128][40];
    __shared__ unsigned short Bsl[128][40];
    const int f32u = flags[0];
    const int z = blockIdx.z;
    const void* W = z == 0 ? W0 : (z == 1 ? W1 : W2);
    const void* bias = z == 0 ? b0 : (z == 1 ? b1 : b2);
    unsigned short* outp = z == 0 ? q : (z == 1 ? kk_ : v);
    const int m0 = blockIdx.y * 128, n0 = blockIdx.x * 128;
    const int t = threadIdx.x;
    const int w = t >> 6, lane = t & 63;
    const int wr = w >> 1, wc = w & 1;
    const int lm = lane & 15, lg = lane >> 4;

    f32x4 acc[4][4] = {};

    for (int k0 = 0; k0 < 1024; k0 += 32) {
        {
            int m = t >> 1, half = t & 1;
            int base = (m0 + m) * 1024 + k0 + half * 16;
            ushort4* dst = (ushort4*)&Asl[m][half * 16];
#pragma unroll
            for (int u = 0; u < 4; ++u) {
                float4 av = ldf4(X, base + 4 * u, f32u);
                ushort4 uv = {f2b(av.x), f2b(av.y), f2b(av.z), f2b(av.w)};
                dst[u] = uv;
            }
        }
        {
            int n = t & 127, kq = (t >> 7) * 16;
#pragma unroll
            for (int qi = 0; qi < 16; qi += 2) {
                float x0 = ldf(W, (k0 + kq + qi) * 1024 + n0 + n, f32u);
                float x1 = ldf(W, (k0 + kq + qi + 1) * 1024 + n0 + n, f32u);
                unsigned int pk = (unsigned int)f2b(x0) | ((unsigned int)f2b(x1) << 16);
                *(unsigned int*)&Bsl[n][kq + qi] = pk;
            }
        }
        __syncthreads();
        bf16x8 af[4], bfr[4];
#pragma unroll
        for (int mi = 0; mi < 4; ++mi)
            af[mi] = *(const bf16x8*)&Asl[wr * 64 + mi * 16 + lm][lg * 8];
#pragma unroll
        for (int nj = 0; nj < 4; ++nj)
            bfr[nj] = *(const bf16x8*)&Bsl[wc * 64 + nj * 16 + lm][lg * 8];
#pragma unroll
        for (int mi = 0; mi < 4; ++mi)
#pragma unroll
            for (int nj = 0; nj < 4; ++nj)
                acc[mi][nj] = __builtin_amdgcn_mfma_f32_16x16x32_bf16(af[mi], bfr[nj],
                                                                      acc[mi][nj], 0, 0, 0);
        __syncthreads();
    }
#pragma unroll
    for (int nj = 0; nj < 4; ++nj) {
        int n = n0 + wc * 64 + nj * 16 + lm;
        float bv = ldf(bias, n, f32u);
        int hh = n >> 6, dd = n & 63;
#pragma unroll
        for (int mi = 0; mi < 4; ++mi) {
#pragma unroll
            for (int r = 0; r < 4; ++r) {
                int m = m0 + wr * 64 + mi * 16 + lg * 4 + r;
                int bb = m >> 10, ii = m & 1023;
                outp[((bb * H_ + hh) * S_ + ii) * DH + dd] = f2b(acc[mi][nj][r] + bv);
            }
        }
    }
}

// ---------------- MFMA GEMM: ctx(bf16) @ Wo + bo -> f32 d_out ----------------
__global__ __launch_bounds__(256) void gemm_out_mfma(const unsigned short* __restrict__ X,
                                                     const void* __restrict__ W,
                                                     const void* __restrict__ bias,
                                                     const int* __restrict__ flags,
                                                     float* __restrict__ out) {
    __shared__ unsigned short Asl[128][40];
    __shared__ unsigned short Bsl[128][40];
    const int f32u = flags[0];
    const int m0 = blockIdx.y * 128, n0 = blockIdx.x * 128;
    const int t = threadIdx.x;
    const int w = t >> 6, lane = t & 63;
    const int wr = w >> 1, wc = w & 1;
    const int lm = lane & 15, lg = lane >> 4;

    f32x4 acc[4][4] = {};

    for (int k0 = 0; k0 < 1024; k0 += 32) {
        {
            int m = t >> 1, half = t & 1;
            const ushort4* src = (const ushort4*)&X[(m0 + m) * 1024 + k0 + half * 16];
            ushort4* dst = (ushort4*)&Asl[m][half * 16];
#pragma unroll
            for (int u = 0; u < 4; ++u) dst[u] = src[u];
        }
        {
            int n = t & 127, kq = (t >> 7) * 16;
#pragma unroll
            for (int qi = 0; qi < 16; qi += 2) {
                float x0 = ldf(W, (k0 + kq + qi) * 1024 + n0 + n, f32u);
                float x1 = ldf(W, (k0 + kq + qi + 1) * 1024 + n0 + n, f32u);
                unsigned int pk = (unsigned int)f2b(x0) | ((unsigned int)f2b(x1) << 16);
                *(unsigned int*)&Bsl[n][kq + qi] = pk;
            }
        }
        __syncthreads();
        bf16x8 af[4], bfr[4];
#pragma unroll
        for (int mi = 0; mi < 4; ++mi)
            af[mi] = *(const bf16x8*)&Asl[wr * 64 + mi * 16 + lm][lg * 8];
#pragma unroll
        for (int nj = 0; nj < 4; ++nj)
            bfr[nj] = *(const bf16x8*)&Bsl[wc * 64 + nj * 16 + lm][lg * 8];
#pragma unroll
        for (int mi = 0; mi < 4; ++mi)
#pragma unroll
            for (int nj = 0; nj < 4; ++nj)
                acc[mi][nj] = __builtin_amdgcn_mfma_f32_16x16x32_bf16(af[mi], bfr[nj],
                                                                      acc[mi][nj], 0, 0, 0);
        __syncthreads();
    }
#pragma unroll
    for (int nj = 0; nj < 4; ++nj) {
        int n = n0 + wc * 64 + nj * 16 + lm;
        float bv = ldf(bias, n, f32u);
#pragma unroll
        for (int mi = 0; mi < 4; ++mi) {
#pragma unroll
            for (int r = 0; r < 4; ++r) {
                int m = m0 + wr * 64 + mi * 16 + lg * 4 + r;
                out[m * 1024 + n] = acc[mi][nj][r] + bv;
            }
        }
    }
}

// ---------------- raw_p2c (bf16 in/out) ----------------
__global__ __launch_bounds__(256) void rel_p2c(const unsigned short* __restrict__ kws,
                                               const void* __restrict__ relq,
                                               const int* __restrict__ flags,
                                               unsigned short* __restrict__ p2c) {
    __shared__ float kt[64][68];
    __shared__ float rq[33][68];
    const int f32u = flags[0];
    const int bh = blockIdx.y, h = bh & 15;
    const int j0 = blockIdx.x * 64;
    const int t = threadIdx.x;
#pragma unroll
    for (int qq = 0; qq < 4; ++qq) {
        int idx = t + 256 * qq;
        int j = idx >> 4, d4 = idx & 15;
        *(float4*)&kt[j][d4 * 4] = ldb4(kws, (bh * S_ + j0 + j) * DH + d4 * 4);
    }
    for (int idx = t; idx < 33 * 16; idx += 256) {
        int k = idx >> 4, d4 = idx & 15;
        *(float4*)&rq[k][d4 * 4] = ldf4(relq, (h * K_ + k) * DH + d4 * 4, f32u);
    }
    __syncthreads();
    for (int o = t; o < 33 * 64; o += 256) {
        int k = o >> 6, j = o & 63;
        float s = 0.f;
#pragma unroll
        for (int d4 = 0; d4 < 16; ++d4) {
            float4 a = *(const float4*)&rq[k][d4 * 4];
            float4 b = *(const float4*)&kt[j][d4 * 4];
            s += a.x * b.x + a.y * b.y + a.z * b.z + a.w * b.w;
        }
        p2c[(bh * K_ + k) * S_ + j0 + j] = f2b(s * SCALE);
    }
}

// ---------------- raw_c2p (bf16 in/out) ----------------
__global__ __launch_bounds__(256) void rel_c2p(const unsigned short* __restrict__ qws,
                                               const void* __restrict__ relk,
                                               const int* __restrict__ flags,
                                               unsigned short* __restrict__ c2p) {
    __shared__ float qt[64][68];
    __shared__ float rk[33][68];
    const int f32u = flags[0];
    const int bh = blockIdx.y, h = bh & 15;
    const int i0 = blockIdx.x * 64;
    const int t = threadIdx.x;
#pragma unroll
    for (int qq = 0; qq < 4; ++qq) {
        int idx = t + 256 * qq;
        int i = idx >> 4, d4 = idx & 15;
        *(float4*)&qt[i][d4 * 4] = ldb4(qws, (bh * S_ + i0 + i) * DH + d4 * 4);
    }
    for (int idx = t; idx < 33 * 16; idx += 256) {
        int k = idx >> 4, d4 = idx & 15;
        *(float4*)&rk[k][d4 * 4] = ldf4(relk, (h * K_ + k) * DH + d4 * 4, f32u);
    }
    __syncthreads();
    for (int o = t; o < 64 * 33; o += 256) {
        int i = o / 33, k = o % 33;
        float s = 0.f;
#pragma unroll
        for (int d4 = 0; d4 < 16; ++d4) {
            float4 a = *(const float4*)&qt[i][d4 * 4];
            float4 b = *(const float4*)&rk[k][d4 * 4];
            s += a.x * b.x + a.y * b.y + a.z * b.z + a.w * b.w;
        }
        c2p[(bh * S_ + i0 + i) * K_ + k] = f2b(s * SCALE);
    }
}

// ---------------- MFMA attention v2: j-chunked, online PV, rowsum from agg ----------------
// Block: 512 thr = 8 waves, 64 q-rows of one (b,h). 4 chunks of 256 j.
// Dynamic LDS (67 KB -> 2 blocks/CU):
//   Ps   [64][256] bf16 swizzled (32 KB)      PS_OFF
//   VT   [64][136] bf16 (V^T, 128-j stage)    VT_OFF
//   c2pS [64][34] bf16; agS [64][34] f32; rvS [33][64] bf16; mfS u8[1024]
#define PS_OFF   0
#define VT_OFF   32768
#define C2P_OFF  50176
#define AG_OFF   54528
#define RV_OFF   63232
#define MF_OFF   67456
#define ATTN_LDS 68480

__device__ __forceinline__ int ps_addr(int il, int jc) {  // jc in 0..255
    return PS_OFF + il * 512 + ((jc * 2) ^ ((il & 7) << 4));
}

__global__ __launch_bounds__(512, 4) void attn_mfma(const unsigned short* __restrict__ qws,
                                                    const unsigned short* __restrict__ kws,
                                                    const unsigned short* __restrict__ vws,
                                                    const unsigned short* __restrict__ p2c,
                                                    const unsigned short* __restrict__ c2p,
                                                    const float* __restrict__ mflag,
                                                    const int* __restrict__ pos,
                                                    const void* __restrict__ relv,
                                                    const int* __restrict__ flags,
                                                    unsigned short* __restrict__ ctxo) {
    extern __shared__ char smem[];
    const int f32u = flags[0];
    const int bh = blockIdx.y, b = bh >> 4, h = bh & 15;
    const int i0 = blockIdx.x * 64;
    const int t = threadIdx.x;
    const int w = t >> 6, lane = t & 63;
    const int lm = lane & 15, lg = lane >> 4;
    const int iband = (w & 3) * 16;     // wave's 16-row i-band
    const int jh = w >> 2;              // wave's j-half within a chunk (phase 1)
    const int dbase = (w >> 2) * 32;    // wave's d-half (PV)

    float* agS = (float*)(smem + AG_OFF);
    unsigned short* c2pS = (unsigned short*)(smem + C2P_OFF);
    unsigned short* rvS = (unsigned short*)(smem + RV_OFF);
    unsigned char* mfS = (unsigned char*)(smem + MF_OFF);

    // ---- phase 0: stage small tables ----
    for (int idx = t; idx < 64 * 33; idx += 512) {
        int il = idx / 33, k = idx % 33;
        c2pS[il * 34 + k] = c2p[(bh * S_ + i0 + il) * K_ + k];
    }
    for (int idx = t; idx < 33 * 64; idx += 512) {
        int k = idx >> 6, d = idx & 63;
        rvS[k * 64 + d] = f2b(ldf(relv, (h * K_ + k) * DH + d, f32u));
    }
    for (int idx = t; idx < 1024; idx += 512)
        mfS[idx] = (mflag[b * S_ + idx] != 0.f) ? 1 : 0;
    for (int idx = t; idx < 64 * 34; idx += 512) agS[idx] = 0.f;

    bf16x8 aq0 = *(const bf16x8*)&qws[(bh * S_ + i0 + iband + lm) * DH + lg * 8];
    bf16x8 aq1 = *(const bf16x8*)&qws[(bh * S_ + i0 + iband + lm) * DH + 32 + lg * 8];
    f32x4 acc0 = {}, acc1 = {};
    __syncthreads();

    for (int c = 0; c < 4; ++c) {
        // ---- phase 1: QK^T + gathers + exp + Ps write + agg ----
        for (int jt = 0; jt < 8; ++jt) {
            const int j0 = c * 256 + jh * 128 + jt * 16;
            bf16x8 kf0 = *(const bf16x8*)&kws[(bh * S_ + j0 + lm) * DH + lg * 8];
            bf16x8 kf1 = *(const bf16x8*)&kws[(bh * S_ + j0 + lm) * DH + 32 + lg * 8];
            f32x4 a = {};
            a = __builtin_amdgcn_mfma_f32_16x16x32_bf16(aq0, kf0, a, 0, 0, 0);
            a = __builtin_amdgcn_mfma_f32_16x16x32_bf16(aq1, kf1, a, 0, 0, 0);
            const int jcol = j0 + lm;
            const int jc = jcol - c * 256;
            const int masked = mfS[jcol];
            const int posrow = (b * S_) * S_ + jcol;
#pragma unroll
            for (int r = 0; r < 4; ++r) {
                int il = iband + lg * 4 + r;
                int i = i0 + il;
                float s = a[r] * SCALE;
                int pb = pos[posrow + i * S_];
                pb = min(max(pb, 0), K_ - 1);
                s += b2f(p2c[(bh * K_ + pb) * S_ + jcol]) + b2f(c2pS[il * 34 + pb]);
                if (masked) s = -1e9f;
                float e = __expf(s);
                *(unsigned short*)(smem + ps_addr(il, jc)) = f2b(e);
                atomicAdd(&agS[il * 34 + pb], e);
            }
        }
        __syncthreads();

        // ---- PV: 2 stages of 128 j ----
        for (int st = 0; st < 2; ++st) {
#pragma unroll
            for (int u = 0; u < 2; ++u) {
                int idx = t + u * 512;          // 0..1023
                int jj = idx >> 3;              // 0..127 (stage-local j)
                int d0 = (idx & 7) * 8;
                int j = c * 256 + st * 128 + jj;
                bf16x8 vv = *(const bf16x8*)&vws[(bh * S_ + j) * DH + d0];
#pragma unroll
                for (int e = 0; e < 8; ++e)
                    *(unsigned short*)(smem + VT_OFF + (d0 + e) * 272 + jj * 2) =
                        ((short*)&vv)[e];
            }
            __syncthreads();
#pragma unroll
            for (int ks = 0; ks < 4; ++ks) {
                int jcb = st * 128 + ks * 32 + lg * 8;   // chunk-local j for Ps
                bf16x8 af = *(const bf16x8*)(smem + ps_addr(iband + lm, jcb));
                bf16x8 b0 = *(const bf16x8*)(smem + VT_OFF + (dbase + lm) * 272 +
                                             (ks * 32 + lg * 8) * 2);
                bf16x8 b1 = *(const bf16x8*)(smem + VT_OFF + (dbase + 16 + lm) * 272 +
                                             (ks * 32 + lg * 8) * 2);
                acc0 = __builtin_amdgcn_mfma_f32_16x16x32_bf16(af, b0, acc0, 0, 0, 0);
                acc1 = __builtin_amdgcn_mfma_f32_16x16x32_bf16(af, b1, acc1, 0, 0, 0);
            }
            __syncthreads();
        }
    }

    // ---- epilogue: rowsum = sum_k agg; + agg @ rel_v; normalize; write ----
#pragma unroll
    for (int r = 0; r < 4; ++r) {
        int il = iband + lg * 4 + r;
        float rs = 0.f;
        float o0 = acc0[r], o1 = acc1[r];
        for (int kb = 0; kb < K_; ++kb) {
            float a = agS[il * 34 + kb];
            rs += a;
            o0 += a * b2f(rvS[kb * 64 + dbase + lm]);
            o1 += a * b2f(rvS[kb * 64 + dbase + 16 + lm]);
        }
        float inv = 1.0f / rs;
        ctxo[(b * S_ + i0 + il) * D_ + h * DH + dbase + lm] = f2b(o0 * inv);
        ctxo[(b * S_ + i0 + il) * D_ + h * DH + dbase + 16 + lm] = f2b(o1 * inv);
    }
}

// ---------------- launcher ----------------
extern "C" void kernel_launch(void* const* d_in, const int* in_sizes, int n_in,
                              void* d_out, int out_size, void* d_ws, size_t ws_size,
                              hipStream_t stream) {
    const void* hidden = d_in[0];
    const void* pos = d_in[1];
    const void* mask = d_in[2];
    const void* Wq = d_in[3];
    const void* bq = d_in[4];
    const void* Wk = d_in[5];
    const void* bk = d_in[6];
    const void* Wv = d_in[7];
    const void* bv = d_in[8];
    const void* Wo = d_in[9];
    const void* bo = d_in[10];
    const void* rq = d_in[11];
    const void* rk = d_in[12];
    const void* rv = d_in[13];

    unsigned char* wsb = (unsigned char*)d_ws;
    size_t o = 0;
    int* flags = (int*)(wsb + o);            o += 256;
    float* mfl = (float*)(wsb + o);          o += 2048 * 4;
    o = (o + 255) & ~(size_t)255;
    unsigned short* qb   = (unsigned short*)(wsb + o); o += 4194304;
    unsigned short* kb   = (unsigned short*)(wsb + o); o += 4194304;
    unsigned short* vb   = (unsigned short*)(wsb + o); o += 4194304;
    unsigned short* p2cb = (unsigned short*)(wsb + o); o += 2162688;
    unsigned short* c2pb = (unsigned short*)(wsb + o); o += 2162688;
    unsigned short* ctxb = (unsigned short*)(wsb + o); o += 4194304;  // ~21.1 MB total

    float* out = (float*)d_out;
    const int* posi = (const int*)pos;

    hipFuncSetAttribute(reinterpret_cast<const void*>(attn_mfma),
                        hipFuncAttributeMaxDynamicSharedMemorySize, ATTN_LDS);

    dim3 tb(256);
    prep<<<dim3(1), tb, 0, stream>>>(hidden, mask, flags, mfl);
    gemm_qkv_mfma<<<dim3(8, 16, 3), tb, 0, stream>>>(hidden, Wq, Wk, Wv, bq, bk, bv,
                                                     flags, qb, kb, vb);
    rel_p2c<<<dim3(16, 32), tb, 0, stream>>>(kb, rq, flags, p2cb);
    rel_c2p<<<dim3(16, 32), tb, 0, stream>>>(qb, rk, flags, c2pb);
    attn_mfma<<<dim3(16, 32), dim3(512), ATTN_LDS, stream>>>(qb, kb, vb, p2cb, c2pb, mfl,
                                                             posi, rv, flags, ctxb);
    gemm_out_mfma<<<dim3(8, 16), tb, 0, stream>>>(ctxb, Wo, bo, flags, out);
}